// Round 2
// baseline (125.181 us; speedup 1.0000x reference)
//
#include <hip/hip_runtime.h>

// GRU stacked: G=2 layers, H=2, T=8, B=2097152.
// One thread per batch element, all state in registers.
// Activations via Pade(5,4) tanh + Newton reciprocal: ZERO transcendental ops.

__device__ __forceinline__ float fast_rcp(float d) {
    // d is always in [945, ~9915] here (strictly positive, normal).
    int i = 0x7EF127EA - __float_as_int(d);
    float r = __int_as_float(i);            // seed, rel err <~6%
    r = r * fmaf(-d, r, 2.0f);              // Newton 1 -> ~3e-3
    r = r * fmaf(-d, r, 2.0f);              // Newton 2 -> ~1e-5
    return r;
}

__device__ __forceinline__ float pade_tanh(float x) {
    // tanh(x) ~= x(945+105u+u^2)/(945+420u+15u^2), u=x^2, clamped at +-3.625.
    // Max abs error ~7e-4 (incl. clamp region).
    float c = fminf(fmaxf(x, -3.625f), 3.625f);   // folds to v_med3_f32
    float u = c * c;
    float num = c * fmaf(u, u + 105.0f, 945.0f);
    float den = fmaf(u, fmaf(u, 15.0f, 420.0f), 945.0f);
    return num * fast_rcp(den);
}

__device__ __forceinline__ float pade_sigmoid(float x) {
    // sigma(x) = 0.5 + 0.5*tanh(x/2); max abs error ~3.5e-4.
    return fmaf(0.5f, pade_tanh(0.5f * x), 0.5f);
}

__global__ __launch_bounds__(256) void gru_fused(
    const float* __restrict__ inputs,   // (B, 2)
    const float* __restrict__ labels,   // (B, 8, 2)
    const float* __restrict__ w_ih,     // (2, 6, 2)
    const float* __restrict__ w_hh,     // (2, 6, 2)
    const float* __restrict__ b_ih,     // (2, 6)
    float* __restrict__ out,            // (B, 8, 2)
    double* __restrict__ loss_acc,
    int B)
{
    const int b = blockIdx.x * blockDim.x + threadIdx.x;
    if (b >= B) return;

    // Wave-uniform weight loads (scalar regs).
    float wih[2][6][2], whh[2][6][2], bih[2][6];
#pragma unroll
    for (int g = 0; g < 2; ++g) {
#pragma unroll
        for (int j = 0; j < 6; ++j) {
            wih[g][j][0] = w_ih[g * 12 + j * 2 + 0];
            wih[g][j][1] = w_ih[g * 12 + j * 2 + 1];
            whh[g][j][0] = w_hh[g * 12 + j * 2 + 0];
            whh[g][j][1] = w_hh[g * 12 + j * 2 + 1];
            bih[g][j]    = b_ih[g * 6 + j];
        }
    }

    const float2 x = reinterpret_cast<const float2*>(inputs)[b];
    const float4* labv = reinterpret_cast<const float4*>(labels) + (size_t)b * 4;
    float4 lab[4];
#pragma unroll
    for (int q = 0; q < 4; ++q) lab[q] = labv[q];   // issued early

    float h[2][2] = {{0.f, 0.f}, {0.f, 0.f}};
    float o0 = x.x, o1 = x.y;
    float res[16];

#pragma unroll
    for (int t = 0; t < 8; ++t) {
#pragma unroll
        for (int g = 0; g < 2; ++g) {
            float gi[6], gh[6];
#pragma unroll
            for (int j = 0; j < 6; ++j) {
                gi[j] = fmaf(o0, wih[g][j][0], fmaf(o1, wih[g][j][1], bih[g][j]));
                gh[j] = fmaf(h[g][0], whh[g][j][0], h[g][1] * whh[g][j][1]);
            }
            const float r0 = pade_sigmoid(gi[0] + gh[0]);
            const float r1 = pade_sigmoid(gi[1] + gh[1]);
            const float z0 = pade_sigmoid(gi[2] + gh[2]);
            const float z1 = pade_sigmoid(gi[3] + gh[3]);
            const float n0 = pade_tanh(fmaf(r0, gh[4], gi[4]));
            const float n1 = pade_tanh(fmaf(r1, gh[5], gi[5]));
            // h' = (1-z)*n + z*h = n + z*(h-n)
            h[g][0] = fmaf(z0, h[g][0] - n0, n0);
            h[g][1] = fmaf(z1, h[g][1] - n1, n1);
            o0 = h[g][0];
            o1 = h[g][1];
        }
        res[t * 2 + 0] = o0;
        res[t * 2 + 1] = o1;
    }

    // Store ret (4x float4 contiguous per thread) + local squared-error sum.
    float4* outv = reinterpret_cast<float4*>(out) + (size_t)b * 4;
    float lsum = 0.f;
#pragma unroll
    for (int q = 0; q < 4; ++q) {
        const float4 ov = make_float4(res[q * 4 + 0], res[q * 4 + 1],
                                      res[q * 4 + 2], res[q * 4 + 3]);
        outv[q] = ov;
        const float d0 = ov.x - lab[q].x;
        const float d1 = ov.y - lab[q].y;
        const float d2 = ov.z - lab[q].z;
        const float d3 = ov.w - lab[q].w;
        lsum += d0 * d0 + d1 * d1 + d2 * d2 + d3 * d3;
    }

    // Wave64 shuffle reduce -> LDS across 4 waves -> one double atomic per block.
#pragma unroll
    for (int off = 32; off > 0; off >>= 1)
        lsum += __shfl_down(lsum, off, 64);
    __shared__ float wsum[4];
    const int lane = threadIdx.x & 63;
    const int wid  = threadIdx.x >> 6;
    if (lane == 0) wsum[wid] = lsum;
    __syncthreads();
    if (threadIdx.x == 0) {
        const float s = (wsum[0] + wsum[1]) + (wsum[2] + wsum[3]);
        atomicAdd(loss_acc, (double)s);
    }
}

__global__ void gru_loss_finalize(const double* __restrict__ acc,
                                  float* __restrict__ loss_out,
                                  double inv_n)
{
    *loss_out = (float)(*acc * inv_n);
}

extern "C" void kernel_launch(void* const* d_in, const int* in_sizes, int n_in,
                              void* d_out, int out_size, void* d_ws, size_t ws_size,
                              hipStream_t stream) {
    const float* inputs = (const float*)d_in[0];
    const float* labels = (const float*)d_in[1];
    const float* w_ih   = (const float*)d_in[2];
    const float* w_hh   = (const float*)d_in[3];
    const float* b_ih   = (const float*)d_in[4];
    float* out  = (float*)d_out;
    double* acc = (double*)d_ws;

    const int B  = in_sizes[0] / 2;   // inputs is (B, H=2)
    const int NE = B * 16;            // B*T*H ret elements

    hipMemsetAsync(d_ws, 0, sizeof(double), stream);

    const int block = 256;
    const int grid  = (B + block - 1) / block;
    gru_fused<<<grid, block, 0, stream>>>(inputs, labels, w_ih, w_hh, b_ih, out, acc, B);
    gru_loss_finalize<<<1, 1, 0, stream>>>(acc, out + NE, 1.0 / (double)NE);
}

// Round 3
// 120.493 us; speedup vs baseline: 1.0389x; 1.0389x over previous
//
#include <hip/hip_runtime.h>

// GRU stacked: G=2 layers, H=2, T=8, B=2097152.
// One thread per batch element. The H=2 pair is packed into <2 x float> so
// the backend emits v_pk_fma_f32/v_pk_mul_f32/v_pk_add_f32 (gfx950 packed
// fp32, 2 FLOP/lane/cy). 2x2 matvec via diag/anti-diag packing:
//   y = wA*x + wB*swap(x),  wA=(w00,w11), wB=(w01,w10).
// Activations: Pade(5,4) tanh clamped at +-3.625 + hardware v_rcp_f32
// (trans pipe overlaps packed VALU; only 6 rcp per cell).

typedef float v2f __attribute__((ext_vector_type(2)));

__device__ __forceinline__ v2f v2(float a, float b) { v2f r; r.x = a; r.y = b; return r; }
__device__ __forceinline__ v2f vbc(float a) { return v2(a, a); }
__device__ __forceinline__ v2f vswap(v2f a) { return __builtin_shufflevector(a, a, 1, 0); }
__device__ __forceinline__ v2f vfma(v2f a, v2f b, v2f c) { return __builtin_elementwise_fma(a, b, c); }

__device__ __forceinline__ v2f pade_tanh2(v2f x) {
    // tanh(x) ~= x(945+105u+u^2)/(945+420u+15u^2), u=x^2, clamp +-3.625.
    // Max abs error ~1.4e-3 (at clamp knee); passed at 2e-3 absmax last round.
    v2f c = __builtin_elementwise_min(__builtin_elementwise_max(x, vbc(-3.625f)), vbc(3.625f));
    v2f u = c * c;
    v2f num = c * vfma(u, u + vbc(105.0f), vbc(945.0f));
    v2f den = vfma(u, vfma(u, vbc(15.0f), vbc(420.0f)), vbc(945.0f));
    v2f rc = v2(__builtin_amdgcn_rcpf(den.x), __builtin_amdgcn_rcpf(den.y));
    return num * rc;
}

__device__ __forceinline__ v2f pade_sig2(v2f x) {
    // sigma(x) = 0.5 + 0.5*tanh(x/2)
    return vfma(vbc(0.5f), pade_tanh2(vbc(0.5f) * x), vbc(0.5f));
}

__global__ __launch_bounds__(256) void gru_fused(
    const float* __restrict__ inputs,   // (B, 2)
    const float* __restrict__ labels,   // (B, 8, 2)
    const float* __restrict__ w_ih,     // (2, 6, 2)
    const float* __restrict__ w_hh,     // (2, 6, 2)
    const float* __restrict__ b_ih,     // (2, 6)
    float* __restrict__ out,            // (B, 8, 2)
    double* __restrict__ loss_acc,
    int B)
{
    const int b = blockIdx.x * blockDim.x + threadIdx.x;
    if (b >= B) return;

    // Wave-uniform packed weights. Gate pair p covers rows (2p, 2p+1):
    // p=0 -> r, p=1 -> z, p=2 -> n.
    v2f wihA[2][3], wihB[2][3], whhA[2][3], whhB[2][3], bpk[2][3];
#pragma unroll
    for (int g = 0; g < 2; ++g) {
#pragma unroll
        for (int p = 0; p < 3; ++p) {
            const int r0 = g * 12 + (2 * p) * 2;      // row 2p
            const int r1 = g * 12 + (2 * p + 1) * 2;  // row 2p+1
            wihA[g][p] = v2(w_ih[r0 + 0], w_ih[r1 + 1]);
            wihB[g][p] = v2(w_ih[r0 + 1], w_ih[r1 + 0]);
            whhA[g][p] = v2(w_hh[r0 + 0], w_hh[r1 + 1]);
            whhB[g][p] = v2(w_hh[r0 + 1], w_hh[r1 + 0]);
            bpk[g][p]  = v2(b_ih[g * 6 + 2 * p], b_ih[g * 6 + 2 * p + 1]);
        }
    }

    const float2 xin = reinterpret_cast<const float2*>(inputs)[b];
    const float4* labv = reinterpret_cast<const float4*>(labels) + (size_t)b * 4;
    float4 lab[4];
#pragma unroll
    for (int q = 0; q < 4; ++q) lab[q] = labv[q];   // issued early

    v2f h[2] = { vbc(0.0f), vbc(0.0f) };
    v2f o = v2(xin.x, xin.y);
    v2f res[8];

#pragma unroll
    for (int t = 0; t < 8; ++t) {
#pragma unroll
        for (int g = 0; g < 2; ++g) {
            const v2f os = vswap(o);
            const v2f hs = vswap(h[g]);
            // r/z gates: gi + gh + b fused in one 4-deep pk_fma chain.
            v2f rin = vfma(wihA[g][0], o,
                      vfma(wihB[g][0], os,
                      vfma(whhA[g][0], h[g],
                      vfma(whhB[g][0], hs, bpk[g][0]))));
            v2f zin = vfma(wihA[g][1], o,
                      vfma(wihB[g][1], os,
                      vfma(whhA[g][1], h[g],
                      vfma(whhB[g][1], hs, bpk[g][1]))));
            // n gate needs gi_n and gh_n separately (r scales gh_n).
            v2f gin = vfma(wihA[g][2], o, vfma(wihB[g][2], os, bpk[g][2]));
            v2f ghn = vfma(whhA[g][2], h[g], whhB[g][2] * hs);

            const v2f r = pade_sig2(rin);
            const v2f z = pade_sig2(zin);
            const v2f n = pade_tanh2(vfma(r, ghn, gin));
            // h' = n + z*(h - n)
            h[g] = vfma(z, h[g] - n, n);
            o = h[g];
        }
        res[t] = o;
    }

    // Store ret (4x float4 = 64B contiguous per thread) + squared-error sum.
    float4* outv = reinterpret_cast<float4*>(out) + (size_t)b * 4;
    float lsum = 0.0f;
#pragma unroll
    for (int q = 0; q < 4; ++q) {
        const v2f a = res[2 * q], c = res[2 * q + 1];
        const float4 ov = make_float4(a.x, a.y, c.x, c.y);
        outv[q] = ov;
        const float d0 = ov.x - lab[q].x;
        const float d1 = ov.y - lab[q].y;
        const float d2 = ov.z - lab[q].z;
        const float d3 = ov.w - lab[q].w;
        lsum += d0 * d0 + d1 * d1 + d2 * d2 + d3 * d3;
    }

    // Wave64 shuffle reduce -> LDS across 4 waves -> one double atomic per block.
#pragma unroll
    for (int off = 32; off > 0; off >>= 1)
        lsum += __shfl_down(lsum, off, 64);
    __shared__ float wsum[4];
    const int lane = threadIdx.x & 63;
    const int wid  = threadIdx.x >> 6;
    if (lane == 0) wsum[wid] = lsum;
    __syncthreads();
    if (threadIdx.x == 0) {
        const float s = (wsum[0] + wsum[1]) + (wsum[2] + wsum[3]);
        atomicAdd(loss_acc, (double)s);
    }
}

__global__ void gru_loss_finalize(const double* __restrict__ acc,
                                  float* __restrict__ loss_out,
                                  double inv_n)
{
    *loss_out = (float)(*acc * inv_n);
}

extern "C" void kernel_launch(void* const* d_in, const int* in_sizes, int n_in,
                              void* d_out, int out_size, void* d_ws, size_t ws_size,
                              hipStream_t stream) {
    const float* inputs = (const float*)d_in[0];
    const float* labels = (const float*)d_in[1];
    const float* w_ih   = (const float*)d_in[2];
    const float* w_hh   = (const float*)d_in[3];
    const float* b_ih   = (const float*)d_in[4];
    float* out  = (float*)d_out;
    double* acc = (double*)d_ws;

    const int B  = in_sizes[0] / 2;   // inputs is (B, H=2)
    const int NE = B * 16;            // B*T*H ret elements

    hipMemsetAsync(d_ws, 0, sizeof(double), stream);

    const int block = 256;
    const int grid  = (B + block - 1) / block;
    gru_fused<<<grid, block, 0, stream>>>(inputs, labels, w_ih, w_hh, b_ih, out, acc, B);
    gru_loss_finalize<<<1, 1, 0, stream>>>(acc, out + NE, 1.0 / (double)NE);
}

// Round 4
// 88.316 us; speedup vs baseline: 1.4174x; 1.3643x over previous
//
#include <hip/hip_runtime.h>

// GRU stacked: G=2 layers, H=2, T=8, B=2097152.
// One thread per batch element; H=2 pair packed as <2 x float> (v_pk_fma_f32).
// Round-4 changes (attacking the constant ~60us of non-VALU time):
//   1. NO contended atomic: per-block partial -> d_ws, reduced by 2nd kernel.
//   2. LDS-transpose epilogue: every global store/load instruction is a dense
//      1KB/wave (full 128B lines), killing partial-line write RMW.
//   3. Dense label prefetch pinned early via sched_barrier(0).

typedef float v2f __attribute__((ext_vector_type(2)));

__device__ __forceinline__ v2f v2(float a, float b) { v2f r; r.x = a; r.y = b; return r; }
__device__ __forceinline__ v2f vbc(float a) { return v2(a, a); }
__device__ __forceinline__ v2f vswap(v2f a) { return __builtin_shufflevector(a, a, 1, 0); }
__device__ __forceinline__ v2f vfma(v2f a, v2f b, v2f c) { return __builtin_elementwise_fma(a, b, c); }

__device__ __forceinline__ v2f pade_tanh2(v2f x) {
    // tanh(x) ~= x(945+105u+u^2)/(945+420u+15u^2), u=x^2, clamp +-3.625.
    v2f c = __builtin_elementwise_min(__builtin_elementwise_max(x, vbc(-3.625f)), vbc(3.625f));
    v2f u = c * c;
    v2f num = c * vfma(u, u + vbc(105.0f), vbc(945.0f));
    v2f den = vfma(u, vfma(u, vbc(15.0f), vbc(420.0f)), vbc(945.0f));
    return num * v2(__builtin_amdgcn_rcpf(den.x), __builtin_amdgcn_rcpf(den.y));
}

__device__ __forceinline__ v2f pade_sig2(v2f x) {
    return vfma(vbc(0.5f), pade_tanh2(vbc(0.5f) * x), vbc(0.5f));
}

__global__ __launch_bounds__(256) void gru_fused(
    const float* __restrict__ inputs,   // (B, 2)
    const float* __restrict__ labels,   // (B, 8, 2)
    const float* __restrict__ w_ih,     // (2, 6, 2)
    const float* __restrict__ w_hh,     // (2, 6, 2)
    const float* __restrict__ b_ih,     // (2, 6)
    float* __restrict__ out,            // (B, 8, 2)
    float* __restrict__ partials,       // (gridDim.x)
    int B)
{
    __shared__ float lds[256 * 17];     // padded: stride-17 floats/thread
    const int tid = threadIdx.x;
    const int b   = blockIdx.x * 256 + tid;

    // ---- dense label prefetch: float4 index blk*1024 + c*256 + tid ----
    // Each instruction: 64 lanes x 16B contiguous = 1KB dense per wave.
    const float4* labd = reinterpret_cast<const float4*>(labels)
                       + (size_t)blockIdx.x * 1024 + tid;
    float4 lab[4];
#pragma unroll
    for (int c = 0; c < 4; ++c) lab[c] = labd[c * 256];
    const float2 xin = reinterpret_cast<const float2*>(inputs)[b];
    __builtin_amdgcn_sched_barrier(0);  // pin the loads before the compute

    // ---- wave-uniform packed weights (diag/anti-diag 2x2 matvec form) ----
    v2f wihA[2][3], wihB[2][3], whhA[2][3], whhB[2][3], bpk[2][3];
#pragma unroll
    for (int g = 0; g < 2; ++g) {
#pragma unroll
        for (int p = 0; p < 3; ++p) {
            const int r0 = g * 12 + (2 * p) * 2;
            const int r1 = g * 12 + (2 * p + 1) * 2;
            wihA[g][p] = v2(w_ih[r0 + 0], w_ih[r1 + 1]);
            wihB[g][p] = v2(w_ih[r0 + 1], w_ih[r1 + 0]);
            whhA[g][p] = v2(w_hh[r0 + 0], w_hh[r1 + 1]);
            whhB[g][p] = v2(w_hh[r0 + 1], w_hh[r1 + 0]);
            bpk[g][p]  = v2(b_ih[g * 6 + 2 * p], b_ih[g * 6 + 2 * p + 1]);
        }
    }

    v2f h[2] = { vbc(0.0f), vbc(0.0f) };
    v2f o = v2(xin.x, xin.y);
    v2f res[8];

#pragma unroll
    for (int t = 0; t < 8; ++t) {
#pragma unroll
        for (int g = 0; g < 2; ++g) {
            const v2f os = vswap(o);
            const v2f hs = vswap(h[g]);
            v2f rin = vfma(wihA[g][0], o,
                      vfma(wihB[g][0], os,
                      vfma(whhA[g][0], h[g],
                      vfma(whhB[g][0], hs, bpk[g][0]))));
            v2f zin = vfma(wihA[g][1], o,
                      vfma(wihB[g][1], os,
                      vfma(whhA[g][1], h[g],
                      vfma(whhB[g][1], hs, bpk[g][1]))));
            v2f gin = vfma(wihA[g][2], o, vfma(wihB[g][2], os, bpk[g][2]));
            v2f ghn = vfma(whhA[g][2], h[g], whhB[g][2] * hs);

            const v2f r = pade_sig2(rin);
            const v2f z = pade_sig2(zin);
            const v2f n = pade_tanh2(vfma(r, ghn, gin));
            h[g] = vfma(z, h[g] - n, n);   // h' = n + z*(h-n)
            o = h[g];
        }
        res[t] = o;
    }

    // ---- LDS transpose: thread-owned 16 floats -> dense block layout ----
#pragma unroll
    for (int q = 0; q < 8; ++q) {
        lds[tid * 17 + 2 * q + 0] = res[q].x;
        lds[tid * 17 + 2 * q + 1] = res[q].y;
    }
    __syncthreads();

    // Dense stores: instruction c covers 1KB/wave of full 128B lines.
    float4* outd = reinterpret_cast<float4*>(out) + (size_t)blockIdx.x * 1024 + tid;
    float lsum = 0.0f;
#pragma unroll
    for (int c = 0; c < 4; ++c) {
        const int f4   = c * 256 + tid;        // float4 index within block
        const int base = (f4 >> 2) * 17 + (f4 & 3) * 4;
        const float4 ov = make_float4(lds[base + 0], lds[base + 1],
                                      lds[base + 2], lds[base + 3]);
        outd[c * 256] = ov;
        const float d0 = ov.x - lab[c].x;
        const float d1 = ov.y - lab[c].y;
        const float d2 = ov.z - lab[c].z;
        const float d3 = ov.w - lab[c].w;
        lsum += d0 * d0 + d1 * d1 + d2 * d2 + d3 * d3;
    }

    // ---- block reduction -> ONE plain store per block (no atomics) ----
#pragma unroll
    for (int off = 32; off > 0; off >>= 1)
        lsum += __shfl_down(lsum, off, 64);
    __shared__ float wsum[4];
    const int lane = tid & 63;
    const int wid  = tid >> 6;
    if (lane == 0) wsum[wid] = lsum;
    __syncthreads();
    if (tid == 0)
        partials[blockIdx.x] = (wsum[0] + wsum[1]) + (wsum[2] + wsum[3]);
}

__global__ __launch_bounds__(256) void gru_loss_reduce(
    const float* __restrict__ partials, int n,
    float* __restrict__ loss_out, double inv_n)
{
    float s = 0.0f;
    for (int i = threadIdx.x; i < n; i += 256) s += partials[i];
#pragma unroll
    for (int off = 32; off > 0; off >>= 1)
        s += __shfl_down(s, off, 64);
    __shared__ float wsum[4];
    const int lane = threadIdx.x & 63;
    const int wid  = threadIdx.x >> 6;
    if (lane == 0) wsum[wid] = s;
    __syncthreads();
    if (threadIdx.x == 0) {
        const double tot = (double)wsum[0] + (double)wsum[1]
                         + (double)wsum[2] + (double)wsum[3];
        *loss_out = (float)(tot * inv_n);
    }
}

extern "C" void kernel_launch(void* const* d_in, const int* in_sizes, int n_in,
                              void* d_out, int out_size, void* d_ws, size_t ws_size,
                              hipStream_t stream) {
    const float* inputs = (const float*)d_in[0];
    const float* labels = (const float*)d_in[1];
    const float* w_ih   = (const float*)d_in[2];
    const float* w_hh   = (const float*)d_in[3];
    const float* b_ih   = (const float*)d_in[4];
    float* out      = (float*)d_out;
    float* partials = (float*)d_ws;

    const int B    = in_sizes[0] / 2;   // inputs is (B, H=2)
    const int NE   = B * 16;            // B*T*H ret elements
    const int grid = B / 256;           // B is a multiple of 256

    gru_fused<<<grid, 256, 0, stream>>>(inputs, labels, w_ih, w_hh, b_ih,
                                        out, partials, B);
    gru_loss_reduce<<<1, 256, 0, stream>>>(partials, grid, out + NE,
                                           1.0 / (double)NE);
}

// Round 6
// 78.139 us; speedup vs baseline: 1.6020x; 1.1302x over previous
//
#include <hip/hip_runtime.h>

// GRU stacked: G=2 layers, H=2, T=8, B=2097152.
// One thread per batch element; H=2 pair packed as <2 x float> (v_pk_*_f32).
// Round-6 = round-5 with the nontemporal-store type fixed (native clang
// vector instead of HIP_vector_type float4).
//   - Pade(5,4) tanh, clamp +-3.625 via explicit v_med3_f32.
//   - ONE v_rcp per v2f pair: R = rcp(dx*dy); inv = R * swap(d).
//   - sigma's /2 folded into the r/z weight rows at load time.
//   - Non-temporal dense output stores; 1024-thread loss-reduce kernel.

typedef float v2f __attribute__((ext_vector_type(2)));
typedef float v4f __attribute__((ext_vector_type(4)));

__device__ __forceinline__ v2f v2(float a, float b) { v2f r; r.x = a; r.y = b; return r; }
__device__ __forceinline__ v2f vbc(float a) { return v2(a, a); }
__device__ __forceinline__ v2f vswap(v2f a) { return __builtin_shufflevector(a, a, 1, 0); }
__device__ __forceinline__ v2f vfma(v2f a, v2f b, v2f c) { return __builtin_elementwise_fma(a, b, c); }

// tanh(x) ~= x(945+105u+u^2)/(945+420u+15u^2), u=x^2, clamp +-3.625.
// One hardware rcp per pair: den.x*den.y in [8.9e5, 9.8e7] -> safe fp32.
__device__ __forceinline__ v2f pade_tanh2(v2f x) {
    v2f c;
    c.x = __builtin_amdgcn_fmed3f(x.x, -3.625f, 3.625f);
    c.y = __builtin_amdgcn_fmed3f(x.y, -3.625f, 3.625f);
    v2f u = c * c;
    v2f num = c * vfma(u, u + vbc(105.0f), vbc(945.0f));
    v2f den = vfma(u, vfma(u, vbc(15.0f), vbc(420.0f)), vbc(945.0f));
    const float R = __builtin_amdgcn_rcpf(den.x * den.y);
    v2f inv = vbc(R) * vswap(den);
    return num * inv;
}

// sigma(2y) = 0.5 + 0.5*tanh(y); argument arrives pre-halved (weight fold).
__device__ __forceinline__ v2f sig_from_half(v2f y) {
    return vfma(vbc(0.5f), pade_tanh2(y), vbc(0.5f));
}

__global__ __launch_bounds__(256) void gru_fused(
    const float* __restrict__ inputs,   // (B, 2)
    const float* __restrict__ labels,   // (B, 8, 2)
    const float* __restrict__ w_ih,     // (2, 6, 2)
    const float* __restrict__ w_hh,     // (2, 6, 2)
    const float* __restrict__ b_ih,     // (2, 6)
    float* __restrict__ out,            // (B, 8, 2)
    float* __restrict__ partials)       // (gridDim.x)
{
    __shared__ float lds[256 * 17];     // stride 17 floats/thread (odd -> 2-way max)
    const int tid = threadIdx.x;
    const int b   = blockIdx.x * 256 + tid;

    // Dense label prefetch: each instruction covers 1KB/wave of full lines.
    const v4f* labd = reinterpret_cast<const v4f*>(labels)
                    + (size_t)blockIdx.x * 1024 + tid;
    v4f lab[4];
#pragma unroll
    for (int c = 0; c < 4; ++c) lab[c] = labd[c * 256];
    const float2 xin = reinterpret_cast<const float2*>(inputs)[b];
    __builtin_amdgcn_sched_barrier(0);  // pin loads before compute

    // Wave-uniform packed weights (diag/anti-diag 2x2 matvec form).
    // Gate pair p: p=0 -> r, p=1 -> z (both scaled by 0.5 for the sigmoid
    // half-angle fold), p=2 -> n (unscaled).
    v2f wihA[2][3], wihB[2][3], whhA[2][3], whhB[2][3], bpk[2][3];
#pragma unroll
    for (int g = 0; g < 2; ++g) {
#pragma unroll
        for (int p = 0; p < 3; ++p) {
            const float hf = (p < 2) ? 0.5f : 1.0f;
            const int r0 = g * 12 + (2 * p) * 2;
            const int r1 = g * 12 + (2 * p + 1) * 2;
            wihA[g][p] = v2(w_ih[r0 + 0] * hf, w_ih[r1 + 1] * hf);
            wihB[g][p] = v2(w_ih[r0 + 1] * hf, w_ih[r1 + 0] * hf);
            whhA[g][p] = v2(w_hh[r0 + 0] * hf, w_hh[r1 + 1] * hf);
            whhB[g][p] = v2(w_hh[r0 + 1] * hf, w_hh[r1 + 0] * hf);
            bpk[g][p]  = v2(b_ih[g * 6 + 2 * p] * hf, b_ih[g * 6 + 2 * p + 1] * hf);
        }
    }

    v2f h[2] = { vbc(0.0f), vbc(0.0f) };
    v2f o = v2(xin.x, xin.y);
    v2f res[8];

#pragma unroll
    for (int t = 0; t < 8; ++t) {
#pragma unroll
        for (int g = 0; g < 2; ++g) {
            const v2f os = vswap(o);
            const v2f hs = vswap(h[g]);
            // r/z pre-activations (already halved via weight fold).
            v2f rin = vfma(wihA[g][0], o,
                      vfma(wihB[g][0], os,
                      vfma(whhA[g][0], h[g],
                      vfma(whhB[g][0], hs, bpk[g][0]))));
            v2f zin = vfma(wihA[g][1], o,
                      vfma(wihB[g][1], os,
                      vfma(whhA[g][1], h[g],
                      vfma(whhB[g][1], hs, bpk[g][1]))));
            v2f gin = vfma(wihA[g][2], o, vfma(wihB[g][2], os, bpk[g][2]));
            v2f ghn = vfma(whhA[g][2], h[g], whhB[g][2] * hs);

            const v2f r = sig_from_half(rin);
            const v2f z = sig_from_half(zin);
            const v2f n = pade_tanh2(vfma(r, ghn, gin));
            h[g] = vfma(z, h[g] - n, n);   // h' = n + z*(h-n)
            o = h[g];
        }
        res[t] = o;
    }

    // LDS transpose: thread-owned 16 floats -> dense block layout.
#pragma unroll
    for (int q = 0; q < 8; ++q) {
        lds[tid * 17 + 2 * q + 0] = res[q].x;
        lds[tid * 17 + 2 * q + 1] = res[q].y;
    }
    __syncthreads();

    // Dense non-temporal stores (1KB/wave/inst) + squared-error accumulation.
    v4f* outd = reinterpret_cast<v4f*>(out) + (size_t)blockIdx.x * 1024 + tid;
    float lsum = 0.0f;
#pragma unroll
    for (int c = 0; c < 4; ++c) {
        const int f4   = c * 256 + tid;
        const int base = (f4 >> 2) * 17 + (f4 & 3) * 4;
        v4f ov;
        ov.x = lds[base + 0]; ov.y = lds[base + 1];
        ov.z = lds[base + 2]; ov.w = lds[base + 3];
        __builtin_nontemporal_store(ov, &outd[c * 256]);
        const v4f d = ov - lab[c];
        lsum += (d.x * d.x + d.y * d.y) + (d.z * d.z + d.w * d.w);
    }

    // Block reduction -> ONE plain store per block (no atomics).
#pragma unroll
    for (int off = 32; off > 0; off >>= 1)
        lsum += __shfl_down(lsum, off, 64);
    __shared__ float wsum[4];
    const int lane = tid & 63;
    const int wid  = tid >> 6;
    if (lane == 0) wsum[wid] = lsum;
    __syncthreads();
    if (tid == 0)
        partials[blockIdx.x] = (wsum[0] + wsum[1]) + (wsum[2] + wsum[3]);
}

__global__ __launch_bounds__(1024) void gru_loss_reduce(
    const v4f* __restrict__ partials4, int n4,
    float* __restrict__ loss_out, double inv_n)
{
    float s = 0.0f;
    for (int i = threadIdx.x; i < n4; i += 1024) {
        const v4f p = partials4[i];
        s += (p.x + p.y) + (p.z + p.w);
    }
#pragma unroll
    for (int off = 32; off > 0; off >>= 1)
        s += __shfl_down(s, off, 64);
    __shared__ float wsum[16];
    const int lane = threadIdx.x & 63;
    const int wid  = threadIdx.x >> 6;
    if (lane == 0) wsum[wid] = s;
    __syncthreads();
    if (threadIdx.x == 0) {
        double tot = 0.0;
#pragma unroll
        for (int i = 0; i < 16; ++i) tot += (double)wsum[i];
        *loss_out = (float)(tot * inv_n);
    }
}

extern "C" void kernel_launch(void* const* d_in, const int* in_sizes, int n_in,
                              void* d_out, int out_size, void* d_ws, size_t ws_size,
                              hipStream_t stream) {
    const float* inputs = (const float*)d_in[0];
    const float* labels = (const float*)d_in[1];
    const float* w_ih   = (const float*)d_in[2];
    const float* w_hh   = (const float*)d_in[3];
    const float* b_ih   = (const float*)d_in[4];
    float* out      = (float*)d_out;
    float* partials = (float*)d_ws;

    const int B    = in_sizes[0] / 2;   // inputs is (B, H=2)
    const int NE   = B * 16;            // B*T*H ret elements
    const int grid = B / 256;           // B is a multiple of 256

    gru_fused<<<grid, 256, 0, stream>>>(inputs, labels, w_ih, w_hh, b_ih,
                                        out, partials);
    gru_loss_reduce<<<1, 1024, 0, stream>>>((const v4f*)partials, grid / 4,
                                            out + NE, 1.0 / (double)NE);
}

// Round 7
// 76.870 us; speedup vs baseline: 1.6285x; 1.0165x over previous
//
#include <hip/hip_runtime.h>

// GRU stacked: G=2 layers, H=2, T=8, B=2097152.
// Round-7: TWO batch elements per thread (independent chains -> ILP-2,
// per-wave prologue/epilogue amortized over 32 outputs). Two-phase LDS
// transpose epilogue keeps LDS at 17408B. Numerics identical to round 6:
//   - Pade(5,4) tanh, clamp +-3.625 via v_med3_f32.
//   - ONE v_rcp per v2f pair: R = rcp(dx*dy); inv = R * swap(d).
//   - sigma's /2 folded into r/z weight rows.
//   - Non-temporal dense output stores; per-block partials, no atomics.

typedef float v2f __attribute__((ext_vector_type(2)));
typedef float v4f __attribute__((ext_vector_type(4)));

__device__ __forceinline__ v2f v2(float a, float b) { v2f r; r.x = a; r.y = b; return r; }
__device__ __forceinline__ v2f vbc(float a) { return v2(a, a); }
__device__ __forceinline__ v2f vswap(v2f a) { return __builtin_shufflevector(a, a, 1, 0); }
__device__ __forceinline__ v2f vfma(v2f a, v2f b, v2f c) { return __builtin_elementwise_fma(a, b, c); }

// tanh(x) ~= x(945+105u+u^2)/(945+420u+15u^2), u=x^2, clamp +-3.625.
// One hardware rcp per pair: den.x*den.y in [8.9e5, 9.8e7] -> safe fp32.
__device__ __forceinline__ v2f pade_tanh2(v2f x) {
    v2f c;
    c.x = __builtin_amdgcn_fmed3f(x.x, -3.625f, 3.625f);
    c.y = __builtin_amdgcn_fmed3f(x.y, -3.625f, 3.625f);
    v2f u = c * c;
    v2f num = c * vfma(u, u + vbc(105.0f), vbc(945.0f));
    v2f den = vfma(u, vfma(u, vbc(15.0f), vbc(420.0f)), vbc(945.0f));
    const float R = __builtin_amdgcn_rcpf(den.x * den.y);
    v2f inv = vbc(R) * vswap(den);
    return num * inv;
}

// sigma(2y) = 0.5 + 0.5*tanh(y); argument arrives pre-halved (weight fold).
__device__ __forceinline__ v2f sig_from_half(v2f y) {
    return vfma(vbc(0.5f), pade_tanh2(y), vbc(0.5f));
}

__device__ __forceinline__ v2f gru_cell(v2f o, v2f h,
    const v2f wihA[3], const v2f wihB[3],
    const v2f whhA[3], const v2f whhB[3], const v2f bpk[3])
{
    const v2f os = vswap(o);
    const v2f hs = vswap(h);
    v2f rin = vfma(wihA[0], o,
              vfma(wihB[0], os,
              vfma(whhA[0], h,
              vfma(whhB[0], hs, bpk[0]))));
    v2f zin = vfma(wihA[1], o,
              vfma(wihB[1], os,
              vfma(whhA[1], h,
              vfma(whhB[1], hs, bpk[1]))));
    v2f gin = vfma(wihA[2], o, vfma(wihB[2], os, bpk[2]));
    v2f ghn = vfma(whhA[2], h, whhB[2] * hs);
    const v2f r = sig_from_half(rin);
    const v2f z = sig_from_half(zin);
    const v2f n = pade_tanh2(vfma(r, ghn, gin));
    return vfma(z, h - n, n);   // h' = n + z*(h-n)
}

__global__ __launch_bounds__(256) void gru_fused(
    const float* __restrict__ inputs,   // (B, 2)
    const float* __restrict__ labels,   // (B, 8, 2)
    const float* __restrict__ w_ih,     // (2, 6, 2)
    const float* __restrict__ w_hh,     // (2, 6, 2)
    const float* __restrict__ b_ih,     // (2, 6)
    float* __restrict__ out,            // (B, 8, 2)
    float* __restrict__ partials)       // (gridDim.x)
{
    __shared__ float lds[256 * 17];     // 17408 B; odd stride -> <=2-way conflicts
    const int tid = threadIdx.x;
    const int e0  = blockIdx.x * 512 + tid;   // phase-A element
    const int e1  = e0 + 256;                 // phase-B element

    const float2 xA = reinterpret_cast<const float2*>(inputs)[e0];
    const float2 xB = reinterpret_cast<const float2*>(inputs)[e1];

    // Wave-uniform packed weights (diag/anti-diag 2x2 matvec form).
    // p=0 -> r, p=1 -> z (scaled 0.5 for sigmoid half-angle), p=2 -> n.
    v2f wihA[2][3], wihB[2][3], whhA[2][3], whhB[2][3], bpk[2][3];
#pragma unroll
    for (int g = 0; g < 2; ++g) {
#pragma unroll
        for (int p = 0; p < 3; ++p) {
            const float hf = (p < 2) ? 0.5f : 1.0f;
            const int r0 = g * 12 + (2 * p) * 2;
            const int r1 = g * 12 + (2 * p + 1) * 2;
            wihA[g][p] = v2(w_ih[r0 + 0] * hf, w_ih[r1 + 1] * hf);
            wihB[g][p] = v2(w_ih[r0 + 1] * hf, w_ih[r1 + 0] * hf);
            whhA[g][p] = v2(w_hh[r0 + 0] * hf, w_hh[r1 + 1] * hf);
            whhB[g][p] = v2(w_hh[r0 + 1] * hf, w_hh[r1 + 0] * hf);
            bpk[g][p]  = v2(b_ih[g * 6 + 2 * p] * hf, b_ih[g * 6 + 2 * p + 1] * hf);
        }
    }

    // Two independent recurrence chains (ILP-2).
    v2f hA[2] = { vbc(0.0f), vbc(0.0f) }, hB[2] = { vbc(0.0f), vbc(0.0f) };
    v2f oA = v2(xA.x, xA.y), oB = v2(xB.x, xB.y);
    v2f resA[8], resB[8];

#pragma unroll
    for (int t = 0; t < 8; ++t) {
#pragma unroll
        for (int g = 0; g < 2; ++g) {
            hA[g] = gru_cell(oA, hA[g], wihA[g], wihB[g], whhA[g], whhB[g], bpk[g]);
            oA = hA[g];
            hB[g] = gru_cell(oB, hB[g], wihA[g], wihB[g], whhA[g], whhB[g], bpk[g]);
            oB = hB[g];
        }
        resA[t] = oA;
        resB[t] = oB;
    }

    // ---- epilogue: issue all 8 dense label loads, then two LDS phases ----
    const v4f* labd = reinterpret_cast<const v4f*>(labels)
                    + (size_t)blockIdx.x * 2048 + tid;
    v4f labA[4], labB[4];
#pragma unroll
    for (int c = 0; c < 4; ++c) labA[c] = labd[c * 256];
#pragma unroll
    for (int c = 0; c < 4; ++c) labB[c] = labd[1024 + c * 256];

    v4f* outd = reinterpret_cast<v4f*>(out) + (size_t)blockIdx.x * 2048 + tid;
    float lsum = 0.0f;

    // Phase A: elements [blk*512, blk*512+256)
#pragma unroll
    for (int q = 0; q < 8; ++q) {
        lds[tid * 17 + 2 * q + 0] = resA[q].x;
        lds[tid * 17 + 2 * q + 1] = resA[q].y;
    }
    __syncthreads();
#pragma unroll
    for (int c = 0; c < 4; ++c) {
        const int f4   = c * 256 + tid;
        const int base = (f4 >> 2) * 17 + (f4 & 3) * 4;
        v4f ov;
        ov.x = lds[base + 0]; ov.y = lds[base + 1];
        ov.z = lds[base + 2]; ov.w = lds[base + 3];
        __builtin_nontemporal_store(ov, &outd[c * 256]);
        const v4f d = ov - labA[c];
        lsum += (d.x * d.x + d.y * d.y) + (d.z * d.z + d.w * d.w);
    }
    __syncthreads();

    // Phase B: elements [blk*512+256, blk*512+512)
#pragma unroll
    for (int q = 0; q < 8; ++q) {
        lds[tid * 17 + 2 * q + 0] = resB[q].x;
        lds[tid * 17 + 2 * q + 1] = resB[q].y;
    }
    __syncthreads();
#pragma unroll
    for (int c = 0; c < 4; ++c) {
        const int f4   = c * 256 + tid;
        const int base = (f4 >> 2) * 17 + (f4 & 3) * 4;
        v4f ov;
        ov.x = lds[base + 0]; ov.y = lds[base + 1];
        ov.z = lds[base + 2]; ov.w = lds[base + 3];
        __builtin_nontemporal_store(ov, &outd[1024 + c * 256]);
        const v4f d = ov - labB[c];
        lsum += (d.x * d.x + d.y * d.y) + (d.z * d.z + d.w * d.w);
    }

    // Block reduction -> ONE plain store per block (no atomics).
#pragma unroll
    for (int off = 32; off > 0; off >>= 1)
        lsum += __shfl_down(lsum, off, 64);
    __shared__ float wsum[4];
    const int lane = tid & 63;
    const int wid  = tid >> 6;
    if (lane == 0) wsum[wid] = lsum;
    __syncthreads();
    if (tid == 0)
        partials[blockIdx.x] = (wsum[0] + wsum[1]) + (wsum[2] + wsum[3]);
}

__global__ __launch_bounds__(1024) void gru_loss_reduce(
    const v4f* __restrict__ partials4, int n4,
    float* __restrict__ loss_out, double inv_n)
{
    float s = 0.0f;
    for (int i = threadIdx.x; i < n4; i += 1024) {
        const v4f p = partials4[i];
        s += (p.x + p.y) + (p.z + p.w);
    }
#pragma unroll
    for (int off = 32; off > 0; off >>= 1)
        s += __shfl_down(s, off, 64);
    __shared__ float wsum[16];
    const int lane = threadIdx.x & 63;
    const int wid  = threadIdx.x >> 6;
    if (lane == 0) wsum[wid] = s;
    __syncthreads();
    if (threadIdx.x == 0) {
        double tot = 0.0;
#pragma unroll
        for (int i = 0; i < 16; ++i) tot += (double)wsum[i];
        *loss_out = (float)(tot * inv_n);
    }
}

extern "C" void kernel_launch(void* const* d_in, const int* in_sizes, int n_in,
                              void* d_out, int out_size, void* d_ws, size_t ws_size,
                              hipStream_t stream) {
    const float* inputs = (const float*)d_in[0];
    const float* labels = (const float*)d_in[1];
    const float* w_ih   = (const float*)d_in[2];
    const float* w_hh   = (const float*)d_in[3];
    const float* b_ih   = (const float*)d_in[4];
    float* out      = (float*)d_out;
    float* partials = (float*)d_ws;

    const int B    = in_sizes[0] / 2;   // inputs is (B, H=2)
    const int NE   = B * 16;            // B*T*H ret elements
    const int grid = B / 512;           // 2 elements per thread

    gru_fused<<<grid, 256, 0, stream>>>(inputs, labels, w_ih, w_hh, b_ih,
                                        out, partials);
    gru_loss_reduce<<<1, 1024, 0, stream>>>((const v4f*)partials, grid / 4,
                                            out + NE, 1.0 / (double)NE);
}

// Round 8
// 59.175 us; speedup vs baseline: 2.1154x; 1.2990x over previous
//
#include <hip/hip_runtime.h>

// GRU stacked: G=2 layers, H=2, T=8, B=2097152.
// Round-8: activations moved to the TRANS pipe (exp2+rcp), freeing the VALU.
//   sigma(x) = rcp(1 + exp2(x'))      with x' = -log2(e)*x   (folded into W)
//   tanh(x)  = 2*rcp(1 + exp2(x'))-1  with x' = -2log2(e)*x  (folded into W)
// Per cell: ~20 pk-VALU insts + 12 scalar trans insts (was ~50 VALU + 3).
// Trans and VALU pipes overlap across waves; ILP-2 (two independent batch
// chains per thread) hides the exp->add->rcp latency chain.
// Epilogue (LDS transpose, dense NT stores, per-block partials) as round 7.

typedef float v2f __attribute__((ext_vector_type(2)));
typedef float v4f __attribute__((ext_vector_type(4)));

__device__ __forceinline__ v2f v2(float a, float b) { v2f r; r.x = a; r.y = b; return r; }
__device__ __forceinline__ v2f vbc(float a) { return v2(a, a); }
__device__ __forceinline__ v2f vswap(v2f a) { return __builtin_shufflevector(a, a, 1, 0); }
__device__ __forceinline__ v2f vfma(v2f a, v2f b, v2f c) { return __builtin_elementwise_fma(a, b, c); }

// rcp(1 + exp2(y)) per component: 2 trans + 1 pk-add + 1 trans*2.
// Saturation-safe: exp2->inf => rcp(inf)=0; exp2->0 => rcp(1)=1.
__device__ __forceinline__ v2f sig_from_scaled(v2f y) {
    v2f e;
    e.x = __builtin_amdgcn_exp2f(y.x);
    e.y = __builtin_amdgcn_exp2f(y.y);
    const v2f d = e + vbc(1.0f);
    v2f q;
    q.x = __builtin_amdgcn_rcpf(d.x);
    q.y = __builtin_amdgcn_rcpf(d.y);
    return q;
}

// One GRU cell; weights arrive pre-scaled: r/z rows by -log2(e), n rows by
// -2log2(e). Returns h' = n + z*(h-n).
__device__ __forceinline__ v2f gru_cell(v2f o, v2f h,
    const v2f wihA[3], const v2f wihB[3],
    const v2f whhA[3], const v2f whhB[3], const v2f bpk[3])
{
    const v2f os = vswap(o);
    const v2f hs = vswap(h);
    v2f rin = vfma(wihA[0], o,
              vfma(wihB[0], os,
              vfma(whhA[0], h,
              vfma(whhB[0], hs, bpk[0]))));
    v2f zin = vfma(wihA[1], o,
              vfma(wihB[1], os,
              vfma(whhA[1], h,
              vfma(whhB[1], hs, bpk[1]))));
    v2f gin = vfma(wihA[2], o, vfma(wihB[2], os, bpk[2]));   // pre-scaled
    v2f ghn = vfma(whhA[2], h, whhB[2] * hs);                // pre-scaled

    const v2f r = sig_from_scaled(rin);
    const v2f z = sig_from_scaled(zin);
    const v2f q = sig_from_scaled(vfma(r, ghn, gin));
    const v2f n = vfma(vbc(2.0f), q, vbc(-1.0f));            // tanh
    return vfma(z, h - n, n);
}

__global__ __launch_bounds__(256) void gru_fused(
    const float* __restrict__ inputs,   // (B, 2)
    const float* __restrict__ labels,   // (B, 8, 2)
    const float* __restrict__ w_ih,     // (2, 6, 2)
    const float* __restrict__ w_hh,     // (2, 6, 2)
    const float* __restrict__ b_ih,     // (2, 6)
    float* __restrict__ out,            // (B, 8, 2)
    float* __restrict__ partials)       // (gridDim.x)
{
    __shared__ float lds[256 * 17];     // 17408 B; odd stride -> <=2-way conflicts
    const int tid = threadIdx.x;
    const int e0  = blockIdx.x * 512 + tid;   // phase-A element
    const int e1  = e0 + 256;                 // phase-B element

    const float2 xA = reinterpret_cast<const float2*>(inputs)[e0];
    const float2 xB = reinterpret_cast<const float2*>(inputs)[e1];

    // Wave-uniform packed weights (diag/anti-diag 2x2 matvec form), with the
    // activation argument scales folded in:
    //   p=0 (r), p=1 (z): scale -log2(e);  p=2 (n): scale -2log2(e).
    v2f wihA[2][3], wihB[2][3], whhA[2][3], whhB[2][3], bpk[2][3];
#pragma unroll
    for (int g = 0; g < 2; ++g) {
#pragma unroll
        for (int p = 0; p < 3; ++p) {
            const float hf = (p < 2) ? -1.442695040888963f : -2.885390081777927f;
            const int r0 = g * 12 + (2 * p) * 2;
            const int r1 = g * 12 + (2 * p + 1) * 2;
            wihA[g][p] = v2(w_ih[r0 + 0] * hf, w_ih[r1 + 1] * hf);
            wihB[g][p] = v2(w_ih[r0 + 1] * hf, w_ih[r1 + 0] * hf);
            whhA[g][p] = v2(w_hh[r0 + 0] * hf, w_hh[r1 + 1] * hf);
            whhB[g][p] = v2(w_hh[r0 + 1] * hf, w_hh[r1 + 0] * hf);
            bpk[g][p]  = v2(b_ih[g * 6 + 2 * p] * hf, b_ih[g * 6 + 2 * p + 1] * hf);
        }
    }

    // Two independent recurrence chains (ILP-2 -> independent trans chains).
    v2f hA[2] = { vbc(0.0f), vbc(0.0f) }, hB[2] = { vbc(0.0f), vbc(0.0f) };
    v2f oA = v2(xA.x, xA.y), oB = v2(xB.x, xB.y);
    v2f resA[8], resB[8];

#pragma unroll
    for (int t = 0; t < 8; ++t) {
#pragma unroll
        for (int g = 0; g < 2; ++g) {
            hA[g] = gru_cell(oA, hA[g], wihA[g], wihB[g], whhA[g], whhB[g], bpk[g]);
            oA = hA[g];
            hB[g] = gru_cell(oB, hB[g], wihA[g], wihB[g], whhA[g], whhB[g], bpk[g]);
            oB = hB[g];
        }
        resA[t] = oA;
        resB[t] = oB;
    }

    // ---- epilogue: dense label loads, then two LDS transpose phases ----
    const v4f* labd = reinterpret_cast<const v4f*>(labels)
                    + (size_t)blockIdx.x * 2048 + tid;
    v4f labA[4], labB[4];
#pragma unroll
    for (int c = 0; c < 4; ++c) labA[c] = labd[c * 256];
#pragma unroll
    for (int c = 0; c < 4; ++c) labB[c] = labd[1024 + c * 256];

    v4f* outd = reinterpret_cast<v4f*>(out) + (size_t)blockIdx.x * 2048 + tid;
    float lsum = 0.0f;

    // Phase A: elements [blk*512, blk*512+256)
#pragma unroll
    for (int q = 0; q < 8; ++q) {
        lds[tid * 17 + 2 * q + 0] = resA[q].x;
        lds[tid * 17 + 2 * q + 1] = resA[q].y;
    }
    __syncthreads();
#pragma unroll
    for (int c = 0; c < 4; ++c) {
        const int f4   = c * 256 + tid;
        const int base = (f4 >> 2) * 17 + (f4 & 3) * 4;
        v4f ov;
        ov.x = lds[base + 0]; ov.y = lds[base + 1];
        ov.z = lds[base + 2]; ov.w = lds[base + 3];
        __builtin_nontemporal_store(ov, &outd[c * 256]);
        const v4f d = ov - labA[c];
        lsum += (d.x * d.x + d.y * d.y) + (d.z * d.z + d.w * d.w);
    }
    __syncthreads();

    // Phase B: elements [blk*512+256, blk*512+512)
#pragma unroll
    for (int q = 0; q < 8; ++q) {
        lds[tid * 17 + 2 * q + 0] = resB[q].x;
        lds[tid * 17 + 2 * q + 1] = resB[q].y;
    }
    __syncthreads();
#pragma unroll
    for (int c = 0; c < 4; ++c) {
        const int f4   = c * 256 + tid;
        const int base = (f4 >> 2) * 17 + (f4 & 3) * 4;
        v4f ov;
        ov.x = lds[base + 0]; ov.y = lds[base + 1];
        ov.z = lds[base + 2]; ov.w = lds[base + 3];
        __builtin_nontemporal_store(ov, &outd[1024 + c * 256]);
        const v4f d = ov - labB[c];
        lsum += (d.x * d.x + d.y * d.y) + (d.z * d.z + d.w * d.w);
    }

    // Block reduction -> ONE plain store per block (no atomics).
#pragma unroll
    for (int off = 32; off > 0; off >>= 1)
        lsum += __shfl_down(lsum, off, 64);
    __shared__ float wsum[4];
    const int lane = tid & 63;
    const int wid  = tid >> 6;
    if (lane == 0) wsum[wid] = lsum;
    __syncthreads();
    if (tid == 0)
        partials[blockIdx.x] = (wsum[0] + wsum[1]) + (wsum[2] + wsum[3]);
}

__global__ __launch_bounds__(1024) void gru_loss_reduce(
    const v4f* __restrict__ partials4, int n4,
    float* __restrict__ loss_out, double inv_n)
{
    float s = 0.0f;
    for (int i = threadIdx.x; i < n4; i += 1024) {
        const v4f p = partials4[i];
        s += (p.x + p.y) + (p.z + p.w);
    }
#pragma unroll
    for (int off = 32; off > 0; off >>= 1)
        s += __shfl_down(s, off, 64);
    __shared__ float wsum[16];
    const int lane = threadIdx.x & 63;
    const int wid  = threadIdx.x >> 6;
    if (lane == 0) wsum[wid] = s;
    __syncthreads();
    if (threadIdx.x == 0) {
        double tot = 0.0;
#pragma unroll
        for (int i = 0; i < 16; ++i) tot += (double)wsum[i];
        *loss_out = (float)(tot * inv_n);
    }
}

extern "C" void kernel_launch(void* const* d_in, const int* in_sizes, int n_in,
                              void* d_out, int out_size, void* d_ws, size_t ws_size,
                              hipStream_t stream) {
    const float* inputs = (const float*)d_in[0];
    const float* labels = (const float*)d_in[1];
    const float* w_ih   = (const float*)d_in[2];
    const float* w_hh   = (const float*)d_in[3];
    const float* b_ih   = (const float*)d_in[4];
    float* out      = (float*)d_out;
    float* partials = (float*)d_ws;

    const int B    = in_sizes[0] / 2;   // inputs is (B, H=2)
    const int NE   = B * 16;            // B*T*H ret elements
    const int grid = B / 512;           // 2 elements per thread

    gru_fused<<<grid, 256, 0, stream>>>(inputs, labels, w_ih, w_hh, b_ih,
                                        out, partials);
    gru_loss_reduce<<<1, 1024, 0, stream>>>((const v4f*)partials, grid / 4,
                                            out + NE, 1.0 / (double)NE);
}